// Round 6
// baseline (318.985 us; speedup 1.0000x reference)
//
#include <hip/hip_runtime.h>
#include <stdint.h>

#define B_ROWS 4096
#define N_ROWS 8192
#define D_DIM  1024
#define NBLK   64          // 8192 / 128 tile blocks per dim
#define NTRI   2080        // 64*65/2 upper-triangular tiles
#define XCDQ   260         // 2080 / 8, exact -> bijective XCD chunk

typedef __attribute__((ext_vector_type(8))) short bf16x8;
typedef __attribute__((ext_vector_type(4))) float f32x4;

// round-to-nearest-even f32 -> bf16
static __device__ __forceinline__ unsigned short f2bf(float f) {
  uint32_t u = __float_as_uint(f);
  u += 0x7fff + ((u >> 16) & 1);
  return (unsigned short)(u >> 16);
}

static __device__ __forceinline__ void async_copy16(const unsigned short* g, unsigned short* l) {
  __builtin_amdgcn_global_load_lds(
      (const __attribute__((address_space(1))) unsigned int*)g,
      (__attribute__((address_space(3))) unsigned int*)l, 16, 0, 0);
}

// raw workgroup barrier: does NOT drain vmcnt (unlike __syncthreads) so
// prefetch global_load_lds stay in flight across it.
static __device__ __forceinline__ void wg_barrier() {
  asm volatile("" ::: "memory");
  __builtin_amdgcn_s_barrier();
  asm volatile("" ::: "memory");
}

// One block per row: L2-normalize, cast to bf16, zero rowsum + done counter.
__global__ __launch_bounds__(256) void normalize_kernel(
    const float* __restrict__ f1, const float* __restrict__ f2,
    unsigned short* __restrict__ F, float* __restrict__ rowsum,
    int* __restrict__ done) {
  const int row = blockIdx.x;
  const int tid = threadIdx.x;
  const float* src = (row < B_ROWS) ? (f1 + (size_t)row * D_DIM)
                                    : (f2 + (size_t)(row - B_ROWS) * D_DIM);
  float4 v = ((const float4*)src)[tid];
  float ss = v.x * v.x + v.y * v.y + v.z * v.z + v.w * v.w;
#pragma unroll
  for (int m = 1; m < 64; m <<= 1) ss += __shfl_xor(ss, m, 64);
  __shared__ float red[4];
  if ((tid & 63) == 0) red[tid >> 6] = ss;
  __syncthreads();
  ss = red[0] + red[1] + red[2] + red[3];
  const float invn = 1.0f / fmaxf(sqrtf(ss), 1e-12f);
  ushort4 o;
  o.x = f2bf(v.x * invn); o.y = f2bf(v.y * invn);
  o.z = f2bf(v.z * invn); o.w = f2bf(v.w * invn);
  ((ushort4*)(F + (size_t)row * D_DIM))[tid] = o;
  if (tid == 0) rowsum[row] = 0.0f;
  if (row == 0 && tid == 0) done[0] = 0;   // kernel boundary flushes this
}

// Fused Gram-GEMM + exp-sum epilogue + LAST-BLOCK FINALIZE over
// UPPER-TRIANGULAR 128x128 tiles. m97-geometry for co-residency: 4 waves
// (2x2, 64x64 each), BK=32, double-buffered 32 KiB LDS. launch_bounds
// (256,4): 124 regs total (60 VGPR + 64 acc) fits 4 waves/SIMD -> 4
// blocks/CU; 2080 blocks / 1024 = 2.03 dispatch rounds (was 2.71 at 3/CU).
// Supertile-column schedule (8x8-tile supertiles) keeps each column's
// B-panels (2 MB) L2-resident; 2080 = 8 XCDs x 260.
__global__ __launch_bounds__(256, 4) void simloss_kernel(
    const unsigned short* __restrict__ F, float* __restrict__ rowsum,
    float* __restrict__ pos, int* __restrict__ done,
    float* __restrict__ out) {
  __shared__ unsigned short lA[2][128 * 32];   // 2 x 8 KiB
  __shared__ unsigned short lB[2][128 * 32];   // 2 x 8 KiB

  // --- L2-locality supertile scheduling (8x8 tiles per supertile) ---
  // chunked bijective XCD remap: XCD x works slots [260x, 260x+260)
  int s = (blockIdx.x & 7) * XCDQ + (blockIdx.x >> 3);
  // supertile column SJ: col SJ holds 64*SJ + 36 tiles (sum = 2080)
  int SJ = 0;
  for (;;) { const int c = 64 * SJ + 36; if (s < c) break; s -= c; ++SJ; }
  int SI = 0;
  while (SI < SJ && s >= 64) { s -= 64; ++SI; }
  int di, dj;
  if (SI < SJ) {            // off-diagonal supertile: dj-major 8-tile groups
    dj = s >> 3; di = s & 7;
  } else {                  // diagonal supertile: upper 36 tiles, dj-major
    dj = 0; while (s > dj) { s -= (dj + 1); ++dj; } di = s;
  }
  const int bi = SI * 8 + di;
  const int bj = SJ * 8 + dj;

  const int tid  = threadIdx.x;
  const int lane = tid & 63;
  const int wv   = __builtin_amdgcn_readfirstlane(tid >> 6);
  const int waveRow = wv >> 1;   // 0..1
  const int waveCol = wv & 1;    // 0..1
  const int q   = lane >> 4;
  const int l16 = lane & 15;

  const int iBase = bi * 128;
  const int jBase = bj * 128;
  const unsigned short* __restrict__ GA = F + (size_t)iBase * D_DIM;
  const unsigned short* __restrict__ GB = F + (size_t)jBase * D_DIM;

  f32x4 acc[4][4];
#pragma unroll
  for (int a = 0; a < 4; ++a)
#pragma unroll
    for (int b = 0; b < 4; ++b) acc[a][b] = (f32x4){0.f, 0.f, 0.f, 0.f};

  // Panel row r (128 rows x 32 cols bf16) = 4 chunks of 16 B.
  // LDS chunk lc = r*4 + c holds global chunk  c ^ ((r>>1)&3)  (bank-spread
  // XOR; pre-swizzled global source, linear LDS dest, same XOR on read).
#define STAGE(BUFI, K0)                                                      \
  {                                                                          \
    _Pragma("unroll") for (int it = 0; it < 2; ++it) {                       \
      const int lc = it * 256 + tid;                                         \
      const int r  = lc >> 2;                                                \
      const int gc = (lc & 3) ^ ((r >> 1) & 3);                              \
      const size_t goff = (size_t)r * D_DIM + (K0) + gc * 8;                 \
      async_copy16(GA + goff, &lA[BUFI][lc * 8]);                            \
      async_copy16(GB + goff, &lB[BUFI][lc * 8]);                            \
    }                                                                        \
  }

  // One K-step (K=32): 8 ds_read_b128 + 16 MFMA per wave.
#define STEP(BUFI)                                                           \
  {                                                                          \
    bf16x8 af[4], bfr[4];                                                    \
    _Pragma("unroll") for (int mi = 0; mi < 4; ++mi) {                       \
      const int r  = waveRow * 64 + mi * 16 + l16;                           \
      const int ch = r * 4 + (q ^ ((r >> 1) & 3));                           \
      af[mi] = *(const bf16x8*)&lA[BUFI][ch * 8];                            \
    }                                                                        \
    _Pragma("unroll") for (int ni = 0; ni < 4; ++ni) {                       \
      const int r  = waveCol * 64 + ni * 16 + l16;                           \
      const int ch = r * 4 + (q ^ ((r >> 1) & 3));                           \
      bfr[ni] = *(const bf16x8*)&lB[BUFI][ch * 8];                           \
    }                                                                        \
    _Pragma("unroll") for (int mi = 0; mi < 4; ++mi)                         \
      _Pragma("unroll") for (int ni = 0; ni < 4; ++ni)                       \
        acc[mi][ni] = __builtin_amdgcn_mfma_f32_16x16x32_bf16(               \
            af[mi], bfr[ni], acc[mi][ni], 0, 0, 0);                          \
  }

  // prologue: stage K-step 0 into buffer 0
  STAGE(0, 0)
  asm volatile("s_waitcnt vmcnt(0)" ::: "memory");
  wg_barrier();

#pragma unroll 1
  for (int t2 = 0; t2 < 16; ++t2) {
    const int k0 = t2 * 64;
    const bool last = (t2 == 15);
    // sub-step A: reads buf0 @k0, prefetches buf1 @k0+32
    STAGE(1, k0 + 32)
    STEP(0)
    asm volatile("s_waitcnt vmcnt(0)" ::: "memory");
    wg_barrier();
    // sub-step B: reads buf1 @k0+32, prefetches buf0 @k0+64
    if (!last) STAGE(0, k0 + 64)
    STEP(1)
    if (!last) asm volatile("s_waitcnt vmcnt(0)" ::: "memory");
    wg_barrier();
  }
#undef STEP
#undef STAGE

  // ---- epilogue ----
  // sim = 10*dot; e = exp(sim-10) excluding diagonal.
  // Row-reduce -> rowsum[i]; for off-diag tiles also column-reduce -> rowsum[j].
  const bool offdiag = (bi != bj);
  float colAcc[4] = {0.f, 0.f, 0.f, 0.f};

#pragma unroll
  for (int mi = 0; mi < 4; ++mi) {
#pragma unroll
    for (int reg = 0; reg < 4; ++reg) {
      const int i = iBase + waveRow * 64 + mi * 16 + q * 4 + reg;
      float s2 = 0.0f;
#pragma unroll
      for (int ni = 0; ni < 4; ++ni) {
        const int j = jBase + waveCol * 64 + ni * 16 + l16;
        const float sim = acc[mi][ni][reg] * 10.0f;
        const float e = (j == i) ? 0.0f : __expf(sim - 10.0f);
        s2 += e;
        colAcc[ni] += e;
        // agent-scope store: finalize reads this from another XCD
        if (i < B_ROWS && j == i + B_ROWS)
          __hip_atomic_store(&pos[i], sim, __ATOMIC_RELAXED,
                             __HIP_MEMORY_SCOPE_AGENT);
      }
      // reduce across the 16 lanes (same q, varying l16) sharing row i
#pragma unroll
      for (int m = 1; m < 16; m <<= 1) s2 += __shfl_xor(s2, m, 64);
      if (l16 == 0) atomicAdd(&rowsum[i], s2);
    }
  }

  if (offdiag) {
    // column sums: reduce across quads (lanes sharing l16); q==0 lanes hold
    // per-column totals for j = jBase + waveCol*64 + ni*16 + l16
#pragma unroll
    for (int ni = 0; ni < 4; ++ni) {
      float c = colAcc[ni];
      c += __shfl_xor(c, 16, 64);
      c += __shfl_xor(c, 32, 64);
      if (q == 0) {
        const int j = jBase + waveCol * 64 + ni * 16 + l16;
        atomicAdd(&rowsum[j], c);
      }
    }
  }

  // ---- last-block finalize (fused; saves a kernel launch) ----
  __threadfence();   // order our atomics/stores before the done increment
  __shared__ int isLast;
  if (tid == 0) {
    const int old = atomicAdd(done, 1);
    isLast = (old == NTRI - 1);
  }
  __syncthreads();   // block-uniform isLast
  if (isLast) {
    float a = 0.0f;
    for (int i = tid; i < N_ROWS; i += 256) {
      // agent-scope loads: values written by blocks on other XCDs
      const float rs = __hip_atomic_load(&rowsum[i], __ATOMIC_RELAXED,
                                         __HIP_MEMORY_SCOPE_AGENT);
      const float ps = __hip_atomic_load(&pos[i & (B_ROWS - 1)],
                                         __ATOMIC_RELAXED,
                                         __HIP_MEMORY_SCOPE_AGENT);
      a += logf(rs) + 10.0f - ps;
    }
#pragma unroll
    for (int m = 1; m < 64; m <<= 1) a += __shfl_xor(a, m, 64);
    __shared__ float red2[4];
    if ((tid & 63) == 0) red2[tid >> 6] = a;
    __syncthreads();
    if (tid == 0)
      out[0] = (red2[0] + red2[1] + red2[2] + red2[3]) * (1.0f / N_ROWS);
  }
}

extern "C" void kernel_launch(void* const* d_in, const int* in_sizes, int n_in,
                              void* d_out, int out_size, void* d_ws, size_t ws_size,
                              hipStream_t stream) {
  const float* f1 = (const float*)d_in[0];
  const float* f2 = (const float*)d_in[1];
  unsigned short* F = (unsigned short*)d_ws;                          // 16 MiB bf16 normalized features
  float* rowsum = (float*)((char*)d_ws + (size_t)N_ROWS * D_DIM * 2); // 32 KiB
  float* pos    = rowsum + N_ROWS;                                    // B_ROWS floats used
  int*   done   = (int*)(pos + B_ROWS);                               // 4 B counter
  float* out    = (float*)d_out;

  hipLaunchKernelGGL(normalize_kernel, dim3(N_ROWS), dim3(256), 0, stream,
                     f1, f2, F, rowsum, done);
  hipLaunchKernelGGL(simloss_kernel, dim3(NTRI), dim3(256), 0, stream,
                     F, rowsum, pos, done, out);
}

// Round 7
// 172.702 us; speedup vs baseline: 1.8470x; 1.8470x over previous
//
#include <hip/hip_runtime.h>
#include <stdint.h>

#define B_ROWS 4096
#define N_ROWS 8192
#define D_DIM  1024
#define NBLK   64          // 8192 / 128 tile blocks per dim
#define NTRI   2080        // 64*65/2 upper-triangular tiles
#define XCDQ   260         // 2080 / 8, exact -> bijective XCD chunk

typedef __attribute__((ext_vector_type(8))) short bf16x8;
typedef __attribute__((ext_vector_type(4))) float f32x4;

// round-to-nearest-even f32 -> bf16
static __device__ __forceinline__ unsigned short f2bf(float f) {
  uint32_t u = __float_as_uint(f);
  u += 0x7fff + ((u >> 16) & 1);
  return (unsigned short)(u >> 16);
}

static __device__ __forceinline__ void async_copy16(const unsigned short* g, unsigned short* l) {
  __builtin_amdgcn_global_load_lds(
      (const __attribute__((address_space(1))) unsigned int*)g,
      (__attribute__((address_space(3))) unsigned int*)l, 16, 0, 0);
}

// raw workgroup barrier: does NOT drain vmcnt (unlike __syncthreads) so
// prefetch global_load_lds stay in flight across it.
static __device__ __forceinline__ void wg_barrier() {
  asm volatile("" ::: "memory");
  __builtin_amdgcn_s_barrier();
  asm volatile("" ::: "memory");
}

// One block per row: L2-normalize, cast to bf16, and zero rowsum.
__global__ __launch_bounds__(256) void normalize_kernel(
    const float* __restrict__ f1, const float* __restrict__ f2,
    unsigned short* __restrict__ F, float* __restrict__ rowsum) {
  const int row = blockIdx.x;
  const int tid = threadIdx.x;
  const float* src = (row < B_ROWS) ? (f1 + (size_t)row * D_DIM)
                                    : (f2 + (size_t)(row - B_ROWS) * D_DIM);
  float4 v = ((const float4*)src)[tid];
  float ss = v.x * v.x + v.y * v.y + v.z * v.z + v.w * v.w;
#pragma unroll
  for (int m = 1; m < 64; m <<= 1) ss += __shfl_xor(ss, m, 64);
  __shared__ float red[4];
  if ((tid & 63) == 0) red[tid >> 6] = ss;
  __syncthreads();
  ss = red[0] + red[1] + red[2] + red[3];
  const float invn = 1.0f / fmaxf(sqrtf(ss), 1e-12f);
  ushort4 o;
  o.x = f2bf(v.x * invn); o.y = f2bf(v.y * invn);
  o.z = f2bf(v.z * invn); o.w = f2bf(v.w * invn);
  ((ushort4*)(F + (size_t)row * D_DIM))[tid] = o;
  if (tid == 0) rowsum[row] = 0.0f;
}

// Fused Gram-GEMM + exp-sum epilogue over UPPER-TRIANGULAR 128x128 tiles.
// m97-geometry for co-residency: 4 waves (2x2, 64x64 each), BK=32.
// TRIPLE-buffered LDS (48 KiB, 3 blocks/CU) with a 2-step-deep counted-
// vmcnt pipeline (T4): per K-step -> vmcnt(4) [drains stage t only, stage
// t+1 stays in flight] -> ONE barrier -> issue stage t+2 -> 8 ds_read +
// 16 MFMA. Each stage gets ~2 K-steps (~800-1000 cyc) of flight, covering
// L3-hit latency. vmcnt(0) only at the last step. Supertile-column
// schedule (8x8-tile supertiles) keeps each column's B-panels (2 MB)
// L2-resident; 2080 = 8 XCDs x 260.
__global__ __launch_bounds__(256, 3) void simloss_kernel(
    const unsigned short* __restrict__ F, float* __restrict__ rowsum,
    float* __restrict__ pos) {
  __shared__ unsigned short lA[3][128 * 32];   // 3 x 8 KiB
  __shared__ unsigned short lB[3][128 * 32];   // 3 x 8 KiB

  // --- L2-locality supertile scheduling (8x8 tiles per supertile) ---
  // chunked bijective XCD remap: XCD x works slots [260x, 260x+260)
  int s = (blockIdx.x & 7) * XCDQ + (blockIdx.x >> 3);
  // supertile column SJ: col SJ holds 64*SJ + 36 tiles (sum = 2080)
  int SJ = 0;
  for (;;) { const int c = 64 * SJ + 36; if (s < c) break; s -= c; ++SJ; }
  int SI = 0;
  while (SI < SJ && s >= 64) { s -= 64; ++SI; }
  int di, dj;
  if (SI < SJ) {            // off-diagonal supertile: dj-major 8-tile groups
    dj = s >> 3; di = s & 7;
  } else {                  // diagonal supertile: upper 36 tiles, dj-major
    dj = 0; while (s > dj) { s -= (dj + 1); ++dj; } di = s;
  }
  const int bi = SI * 8 + di;
  const int bj = SJ * 8 + dj;

  const int tid  = threadIdx.x;
  const int lane = tid & 63;
  const int wv   = __builtin_amdgcn_readfirstlane(tid >> 6);
  const int waveRow = wv >> 1;   // 0..1
  const int waveCol = wv & 1;    // 0..1
  const int q   = lane >> 4;
  const int l16 = lane & 15;

  const int iBase = bi * 128;
  const int jBase = bj * 128;
  const unsigned short* __restrict__ GA = F + (size_t)iBase * D_DIM;
  const unsigned short* __restrict__ GB = F + (size_t)jBase * D_DIM;

  f32x4 acc[4][4];
#pragma unroll
  for (int a = 0; a < 4; ++a)
#pragma unroll
    for (int b = 0; b < 4; ++b) acc[a][b] = (f32x4){0.f, 0.f, 0.f, 0.f};

  // Panel row r (128 rows x 32 cols bf16) = 4 chunks of 16 B.
  // LDS chunk lc = r*4 + c holds global chunk  c ^ ((r>>1)&3)  (bank-spread
  // XOR; pre-swizzled global source, linear LDS dest, same XOR on read).
#define STAGE(BUFI, K0)                                                      \
  {                                                                          \
    _Pragma("unroll") for (int it = 0; it < 2; ++it) {                       \
      const int lc = it * 256 + tid;                                         \
      const int r  = lc >> 2;                                                \
      const int gc = (lc & 3) ^ ((r >> 1) & 3);                              \
      const size_t goff = (size_t)r * D_DIM + (K0) + gc * 8;                 \
      async_copy16(GA + goff, &lA[BUFI][lc * 8]);                            \
      async_copy16(GB + goff, &lB[BUFI][lc * 8]);                            \
    }                                                                        \
  }

  // One K-step (K=32): 8 ds_read_b128 + 16 MFMA per wave.
#define STEP(BUFI)                                                           \
  {                                                                          \
    bf16x8 af[4], bfr[4];                                                    \
    _Pragma("unroll") for (int mi = 0; mi < 4; ++mi) {                       \
      const int r  = waveRow * 64 + mi * 16 + l16;                           \
      const int ch = r * 4 + (q ^ ((r >> 1) & 3));                           \
      af[mi] = *(const bf16x8*)&lA[BUFI][ch * 8];                            \
    }                                                                        \
    _Pragma("unroll") for (int ni = 0; ni < 4; ++ni) {                       \
      const int r  = waveCol * 64 + ni * 16 + l16;                           \
      const int ch = r * 4 + (q ^ ((r >> 1) & 3));                           \
      bfr[ni] = *(const bf16x8*)&lB[BUFI][ch * 8];                           \
    }                                                                        \
    _Pragma("unroll") for (int mi = 0; mi < 4; ++mi)                         \
      _Pragma("unroll") for (int ni = 0; ni < 4; ++ni)                       \
        acc[mi][ni] = __builtin_amdgcn_mfma_f32_16x16x32_bf16(               \
            af[mi], bfr[ni], acc[mi][ni], 0, 0, 0);                          \
  }

  // prologue: stage K-steps 0 and 1 (8 loads/thread in flight)
  STAGE(0, 0)
  STAGE(1, 32)

  // main loop: 32 K-steps, one barrier + one counted vmcnt each
#pragma unroll 1
  for (int t = 0; t < 32; ++t) {
    if (t == 31) { asm volatile("s_waitcnt vmcnt(0)" ::: "memory"); }
    else         { asm volatile("s_waitcnt vmcnt(4)" ::: "memory"); }
    wg_barrier();
    if (t < 30) { STAGE((t + 2) % 3, (t + 2) * 32) }
    STEP(t % 3)
  }
#undef STEP
#undef STAGE

  // ---- epilogue ----
  // sim = 10*dot; e = exp(sim-10) excluding diagonal.
  // Row-reduce -> rowsum[i]; for off-diag tiles also column-reduce -> rowsum[j].
  const bool offdiag = (bi != bj);
  float colAcc[4] = {0.f, 0.f, 0.f, 0.f};

#pragma unroll
  for (int mi = 0; mi < 4; ++mi) {
#pragma unroll
    for (int reg = 0; reg < 4; ++reg) {
      const int i = iBase + waveRow * 64 + mi * 16 + q * 4 + reg;
      float s2 = 0.0f;
#pragma unroll
      for (int ni = 0; ni < 4; ++ni) {
        const int j = jBase + waveCol * 64 + ni * 16 + l16;
        const float sim = acc[mi][ni][reg] * 10.0f;
        const float e = (j == i) ? 0.0f : __expf(sim - 10.0f);
        s2 += e;
        colAcc[ni] += e;
        if (i < B_ROWS && j == i + B_ROWS) pos[i] = sim;
      }
      // reduce across the 16 lanes (same q, varying l16) sharing row i
#pragma unroll
      for (int m = 1; m < 16; m <<= 1) s2 += __shfl_xor(s2, m, 64);
      if (l16 == 0) atomicAdd(&rowsum[i], s2);
    }
  }

  if (offdiag) {
    // column sums: reduce across quads (lanes sharing l16); q==0 lanes hold
    // per-column totals for j = jBase + waveCol*64 + ni*16 + l16
#pragma unroll
    for (int ni = 0; ni < 4; ++ni) {
      float c = colAcc[ni];
      c += __shfl_xor(c, 16, 64);
      c += __shfl_xor(c, 32, 64);
      if (q == 0) {
        const int j = jBase + waveCol * 64 + ni * 16 + l16;
        atomicAdd(&rowsum[j], c);
      }
    }
  }
}

__global__ __launch_bounds__(1024) void finalize_kernel(
    const float* __restrict__ rowsum, const float* __restrict__ pos,
    float* __restrict__ out) {
  const int tid = threadIdx.x;
  float a = 0.0f;
  for (int i = tid; i < N_ROWS; i += 1024)
    a += logf(rowsum[i]) + 10.0f - pos[i & (B_ROWS - 1)];
#pragma unroll
  for (int m = 1; m < 64; m <<= 1) a += __shfl_xor(a, m, 64);
  __shared__ float red[16];
  if ((tid & 63) == 0) red[tid >> 6] = a;
  __syncthreads();
  if (tid == 0) {
    float t = 0.0f;
#pragma unroll
    for (int w = 0; w < 16; ++w) t += red[w];
    out[0] = t * (1.0f / N_ROWS);
  }
}

extern "C" void kernel_launch(void* const* d_in, const int* in_sizes, int n_in,
                              void* d_out, int out_size, void* d_ws, size_t ws_size,
                              hipStream_t stream) {
  const float* f1 = (const float*)d_in[0];
  const float* f2 = (const float*)d_in[1];
  unsigned short* F = (unsigned short*)d_ws;                          // 16 MiB bf16 normalized features
  float* rowsum = (float*)((char*)d_ws + (size_t)N_ROWS * D_DIM * 2); // 32 KiB
  float* pos    = rowsum + N_ROWS;                                    // 16 KiB used (i < B_ROWS)
  float* out    = (float*)d_out;

  hipLaunchKernelGGL(normalize_kernel, dim3(N_ROWS), dim3(256), 0, stream, f1, f2, F, rowsum);
  hipLaunchKernelGGL(simloss_kernel, dim3(NTRI), dim3(256), 0, stream, F, rowsum, pos);
  hipLaunchKernelGGL(finalize_kernel, dim3(1), dim3(1024), 0, stream, rowsum, pos, out);
}